// Round 5
// baseline (81.242 us; speedup 1.0000x reference)
//
#include <hip/hip_runtime.h>
#include <math.h>

// Chamfer distance via MFMA, fp16 quantized / fp32 accumulate.
// K-packing: A_row = (-2ax,-2ay,-2az, 1, sqa, 0,0,0), B_col = (bx,by,bz, sqb, 1, 0,0,0)
// => MFMA dot = sqa + sqb - 2 a.b = full squared distance (from quantized coords).
//
// R14 vs R13: R12/R13 calibration says the fused kernel runs ~35us against a
// ~7us pipe floor, stall-dominated (R11: VALUBusy 37%, MfmaUtil 10%), and
// the only occupancy points ever tested are 1 wave/SIMD (60us) and
// 4 waves/SIMD (~35us). This round buys the HW max, 8 waves/SIMD: B-tile
// halved to 64KB (8192 pts) so 2 blocks/CU co-reside (32 waves/CU). Row-mins
// become per-half partials (256KB) + a reduce dispatch (dispatch cost ~1-2us,
// proven R12). Binding constraint: VGPR <= 64/wave for 8 waves/SIMD ->
// inner loop reshaped for minimum liveness: no SW prefetch (TLP hides LDS
// latency), ds_read_b64 lands directly in the B-operand union, ONE floatx16
// d reused across both MFMAs with plain v_min folds (live ~54 regs).
// Macro: 3 dispatches (memset4B, sweep, reduce), no grid.sync.

typedef _Float16 half8    __attribute__((ext_vector_type(8)));
typedef float    floatx16 __attribute__((ext_vector_type(16)));

constexpr int NPTS = 16384;    // fixed problem size
constexpr int HALF = 8192;     // B points per block (64 KB LDS) -> 2 blocks/CU
constexpr int ROWS = 128;      // A-rows per block (4 row-groups * 32)
constexpr int BLK  = 1024;     // 16 waves; 2 blocks/CU = 32 waves/CU = 8/SIMD

// ---- pack one point into an f16 fragment (x,y,z,|p|^2) ----
__device__ __forceinline__ uint2 pack_point(const float* __restrict__ P, int j)
{
    float x = P[3*j], y = P[3*j+1], z = P[3*j+2];
    _Float16 hx = (_Float16)x, hy = (_Float16)y, hz = (_Float16)z;
    float qx = (float)hx, qy = (float)hy, qz = (float)hz;
    _Float16 hw = (_Float16)(qx*qx + qy*qy + qz*qz);
    union { _Float16 h[4]; uint2 u; } p;
    p.h[0] = hx; p.h[1] = hy; p.h[2] = hz; p.h[3] = hw;
    return p.u;
}

// Sweep: each block = (128 A-rows) x (one B half); writes per-(row,half) partial min^2.
__global__ __launch_bounds__(BLK, 8) void chamfer_sweep_kernel(
    const float* __restrict__ P1, const float* __restrict__ P2,
    float* __restrict__ part, int n1, int n2)
{
    __shared__ uint2 sB[HALF];            // packed B half-cloud (64 KB)
    __shared__ float sRowMin[4][ROWS];    // per-B-quarter row mins

    const int dir   = blockIdx.z;
    const int half  = blockIdx.y;
    const float* PA = dir == 0 ? P1 : P2;
    const float* PB = dir == 0 ? P2 : P1;
    const int nA    = dir == 0 ? n1 : n2;
    const int nB    = dir == 0 ? n2 : n1;

    const int tid  = threadIdx.x;
    const int wave = tid >> 6;
    const int lane = tid & 63;
    const int n    = lane & 31;
    const int g    = lane >> 5;
    const bool g0  = (g == 0);
    const int wr   = wave & 3;        // row-group: rows wr*32 .. wr*32+31
    const int wq   = wave >> 2;       // quarter of the half (2048 pts)

    // ---- pack this B half into LDS (reads are L2-resident) ----
    for (int j = tid; j < HALF; j += BLK) {
        int jg = half * HALF + j;
        int jj = jg < nB ? jg : nB - 1;      // pad with dup of last point
        sB[j] = pack_point(PB, jj);
    }

    // ---- A fragment: pack own row directly from fp32 points ----
    const _Float16 h0 = (_Float16)0.0f;
    half8 af;
    {
        int arow = blockIdx.x * ROWS + wr * 32 + n;
        int j = arow < nA ? arow : nA - 1;
        union { uint2 u; _Float16 h[4]; } au; au.u = pack_point(PA, j);
        const _Float16 m2 = (_Float16)(-2.0f);
        af[0] = g0 ? (_Float16)(au.h[0] * m2) : h0;
        af[1] = g0 ? (_Float16)(au.h[1] * m2) : h0;
        af[2] = g0 ? (_Float16)(au.h[2] * m2) : h0;
        af[3] = g0 ? (_Float16)1.0f : h0;
        af[4] = g0 ? au.h[3] : h0;
        af[5] = h0; af[6] = h0; af[7] = h0;
    }

    __syncthreads();

    floatx16 rowmin;
#pragma unroll
    for (int r = 0; r < 16; ++r) rowmin[r] = 1e30f;
    const floatx16 zacc = {};

    // B-operand unions: upper pair (1.0h,0 | 0,0) written ONCE; ds_read_b64
    // lands directly in the lower pair each step (no prefetch copies -> min
    // register liveness; 8 waves/SIMD provide the latency hiding).
    union BF { half8 v; unsigned u[4]; uint2 lo; };
    BF bu0, bu1;
    { union { _Float16 h[2]; unsigned u; } q;
      q.h[0] = (_Float16)1.0f; q.h[1] = h0;
      bu0.u[2] = q.u; bu0.u[3] = 0u;
      bu1.u[2] = q.u; bu1.u[3] = 0u; }

    // ---- sweep own quarter: 32 steps x (2 ds_read_b64 + 2 MFMA + 32 v_min) ----
    constexpr int QLEN = HALF >> 2;            // 2048
    constexpr int NT   = QLEN / 64;            // 32 steps
    const uint2* qbase = sB + wq * QLEN + n;   // g0/g1 broadcast same addr
    for (int bt = 0; bt < NT; ++bt) {
        const uint2* p = qbase + bt * 64;
        bu0.lo = p[0];
        bu1.lo = p[32];

        floatx16 d = __builtin_amdgcn_mfma_f32_32x32x16_f16(af, bu0.v, zacc, 0, 0, 0);
#pragma unroll
        for (int r = 0; r < 16; ++r) rowmin[r] = fminf(rowmin[r], d[r]);

        d = __builtin_amdgcn_mfma_f32_32x32x16_f16(af, bu1.v, zacc, 0, 0, 0);
#pragma unroll
        for (int r = 0; r < 16; ++r) rowmin[r] = fminf(rowmin[r], d[r]);
    }

    // ---- reduce across the 32 cols (xor-shuffle within n-group) ----
#pragma unroll
    for (int mask = 1; mask <= 16; mask <<= 1)
#pragma unroll
        for (int r = 0; r < 16; ++r)
            rowmin[r] = fminf(rowmin[r], __shfl_xor(rowmin[r], mask));

    if (n == 0) {
#pragma unroll
        for (int r = 0; r < 16; ++r) {
            int rr = wr * 32 + g * 4 + ((r & 3) + 8 * (r >> 2));   // C/D row map
            sRowMin[wq][rr] = rowmin[r];
        }
    }
    __syncthreads();

    // ---- combine quarters -> one partial per (dir,row,half) ----
    if (tid < ROWS) {
        float m = fminf(fminf(sRowMin[0][tid], sRowMin[1][tid]),
                        fminf(sRowMin[2][tid], sRowMin[3][tid]));
        int grow = blockIdx.x * ROWS + tid;
        if (grow < nA)
            part[(size_t)(((dir << 14) + grow) << 1) + half] = m;
    }
}

// Per-row min over 2 half-partials -> sqrt -> block sum -> atomicAdd(out)
__global__ __launch_bounds__(256) void reduce_kernel(
    const float* __restrict__ part, float* __restrict__ out,
    int n1, int n2)
{
    __shared__ float s[256];
    int rr = blockIdx.x * 256 + threadIdx.x;    // [0, 2*16384)
    int dir = rr >> 14, row = rr & 16383;
    float acc = 0.0f;
    if (row < (dir == 0 ? n1 : n2)) {
        const float2 v = ((const float2*)part)[rr];
        acc = sqrtf(fmaxf(fminf(v.x, v.y), 0.0f));
    }
    s[threadIdx.x] = acc;
    __syncthreads();
    for (int w = 128; w > 0; w >>= 1) {
        if (threadIdx.x < w) s[threadIdx.x] += s[threadIdx.x + w];
        __syncthreads();
    }
    if (threadIdx.x == 0) atomicAdd(out, s[0]);
}

extern "C" void kernel_launch(void* const* d_in, const int* in_sizes, int n_in,
                              void* d_out, int out_size, void* d_ws, size_t ws_size,
                              hipStream_t stream) {
    const float* P1 = (const float*)d_in[0];
    const float* P2 = (const float*)d_in[1];
    const int n1 = in_sizes[0] / 3;   // 16384
    const int n2 = in_sizes[1] / 3;   // 16384
    float* part = (float*)d_ws;       // [2 dirs][16384 rows][2 halves] = 256 KB
    float* out  = (float*)d_out;

    hipMemsetAsync(out, 0, sizeof(float), stream);   // capture-safe

    {   // 512 blocks = 2/CU co-resident (64KB LDS each) -> 32 waves/CU
        dim3 grid(NPTS / ROWS, 2, 2);
        chamfer_sweep_kernel<<<grid, BLK, 0, stream>>>(P1, P2, part, n1, n2);
    }
    reduce_kernel<<<(2 * NPTS) / 256, 256, 0, stream>>>(part, out, n1, n2);
}